// Round 2
// baseline (50156.519 us; speedup 1.0000x reference)
//
#include <hip/hip_runtime.h>
#include <hip/hip_bf16.h>

#define N_NODES 100000
#define N_EDGES 1600000

// ---- RK45 (Dormand-Prince) coefficients, fp32 ----
#define Hc   0.1f
#define A21c 0.2f
#define A31c (float)(3.0/40.0)
#define A32c (float)(9.0/40.0)
#define A41c (float)(44.0/45.0)
#define A42c (float)(-56.0/15.0)
#define A43c (float)(32.0/9.0)
#define A51c (float)(19372.0/6561.0)
#define A52c (float)(-25360.0/2187.0)
#define A53c (float)(64448.0/6561.0)
#define A54c (float)(-212.0/729.0)
#define A61c (float)(9017.0/3168.0)
#define A62c (float)(-355.0/33.0)
#define A63c (float)(46732.0/5247.0)
#define A64c (float)(49.0/176.0)
#define A65c (float)(-5103.0/18656.0)
#define B1c  (float)(35.0/384.0)
#define B3c  (float)(500.0/1113.0)
#define B4c  (float)(125.0/192.0)
#define B5c  (float)(-2187.0/6784.0)
#define B6c  (float)(11.0/84.0)

// Zero the segment-sum accumulators in workspace (re-poisoned 0xAA each call).
__global__ void zero_ws_kernel(float4* ws, int n4) {
    int i = blockIdx.x * blockDim.x + threadIdx.x;
    if (i < n4) ws[i] = make_float4(0.f, 0.f, 0.f, 0.f);
}

// Edge phase: encode edges, decode dec_e, scatter-add h_e into sent/recv sums.
__global__ __launch_bounds__(256) void edge_kernel(
    const float* __restrict__ edges,
    const int* __restrict__ senders,
    const int* __restrict__ receivers,
    const float* __restrict__ W,    // (3,10)
    const float* __restrict__ b,    // (10)
    const float* __restrict__ Wd,   // (10,1)
    const float* __restrict__ bd,   // (1)
    float* __restrict__ sent,       // (N_NODES,10) accumulators
    float* __restrict__ recv,       // (N_NODES,10) accumulators
    float* __restrict__ dec_e)      // (N_EDGES)
{
    int e = blockIdx.x * 256 + threadIdx.x;
    if (e >= N_EDGES) return;
    float e0 = edges[e*3+0], e1 = edges[e*3+1], e2 = edges[e*3+2];
    int s = senders[e], r = receivers[e];
    float he[10];
    float d = bd[0];
    #pragma unroll
    for (int j = 0; j < 10; ++j) {
        float v = fmaf(e0, W[j], fmaf(e1, W[10+j], fmaf(e2, W[20+j], b[j])));
        he[j] = v;
        d = fmaf(v, Wd[j], d);
    }
    dec_e[e] = d;
    #pragma unroll
    for (int j = 0; j < 10; ++j) atomicAdd(&sent[s*10+j], he[j]);
    #pragma unroll
    for (int j = 0; j < 10; ++j) atomicAdd(&recv[r*10+j], he[j]);
}

// One derivative eval: out = relu(in @ W1 + b1) @ W2 + b2, all 32-wide.
// Weights/biases in LDS, read wave-uniform (broadcast, conflict-free).
// Peak extra liveness inside: in[32] + t[32].
__device__ __forceinline__ void deriv32(const float4* __restrict__ sW1,
                                        const float4* __restrict__ sW2,
                                        const float4* __restrict__ sB,  // [0..7]=b1, [8..15]=b2
                                        const float* __restrict__ in,
                                        float* __restrict__ out)
{
    float t[32];
    #pragma unroll
    for (int j4 = 0; j4 < 8; ++j4) {
        float4 bb = sB[j4];
        t[4*j4+0] = bb.x; t[4*j4+1] = bb.y; t[4*j4+2] = bb.z; t[4*j4+3] = bb.w;
    }
    #pragma unroll
    for (int i = 0; i < 32; ++i) {
        float v = in[i];
        #pragma unroll
        for (int j4 = 0; j4 < 8; ++j4) {
            float4 w = sW1[i*8 + j4];
            t[4*j4+0] = fmaf(v, w.x, t[4*j4+0]);
            t[4*j4+1] = fmaf(v, w.y, t[4*j4+1]);
            t[4*j4+2] = fmaf(v, w.z, t[4*j4+2]);
            t[4*j4+3] = fmaf(v, w.w, t[4*j4+3]);
        }
    }
    #pragma unroll
    for (int j = 0; j < 32; ++j) t[j] = fmaxf(t[j], 0.0f);
    #pragma unroll
    for (int j4 = 0; j4 < 8; ++j4) {
        float4 bb = sB[8 + j4];
        out[4*j4+0] = bb.x; out[4*j4+1] = bb.y; out[4*j4+2] = bb.z; out[4*j4+3] = bb.w;
    }
    #pragma unroll
    for (int i = 0; i < 32; ++i) {
        float v = t[i];
        #pragma unroll
        for (int j4 = 0; j4 < 8; ++j4) {
            float4 w = sW2[i*8 + j4];
            out[4*j4+0] = fmaf(v, w.x, out[4*j4+0]);
            out[4*j4+1] = fmaf(v, w.y, out[4*j4+1]);
            out[4*j4+2] = fmaf(v, w.z, out[4*j4+2]);
            out[4*j4+3] = fmaf(v, w.w, out[4*j4+3]);
        }
    }
}

// Node phase: encode node, assemble x, integrate 10 RK45 steps, decode outputs.
// Register-liveness-minimized: k2,k3 stashed in LDS ([comp][tid], stride-4B
// across lanes -> conflict-free); y-accumulation folded before k6 so k1..k5
// are dead during the final deriv. Peak reg-resident: y,k1,k4,k5,u,t ~ 192fl.
__global__ __launch_bounds__(256) void node_kernel(
    const float* __restrict__ nodes,     // (N_NODES,2)
    const float* __restrict__ globals_,  // (2)
    const float* __restrict__ encW,      // (2,10)
    const float* __restrict__ encb,      // (10)
    const float* __restrict__ W1,        // (32,32)
    const float* __restrict__ b1,        // (32)
    const float* __restrict__ W2,        // (32,32)
    const float* __restrict__ b2,        // (32)
    const float* __restrict__ Wno,       // (32,10)
    const float* __restrict__ bno,       // (10)
    const float* __restrict__ Wdn,       // (10,1)
    const float* __restrict__ bdn,       // (1)
    const float* __restrict__ sent,      // (N_NODES,10)
    const float* __restrict__ recv,      // (N_NODES,10)
    float* __restrict__ out_decn,        // (N_NODES)
    float* __restrict__ out_pos,         // (N_NODES)
    float* __restrict__ out_vel)         // (N_NODES)
{
    __shared__ float4 sW1[256];
    __shared__ float4 sW2[256];
    __shared__ float4 sB[16];
    __shared__ float k2s[32][256];   // [comp][tid] -> lane-stride 4B, conflict-free
    __shared__ float k3s[32][256];
    {
        int t = threadIdx.x;
        sW1[t] = ((const float4*)W1)[t];
        sW2[t] = ((const float4*)W2)[t];
        if (t < 8)  sB[t]      = ((const float4*)b1)[t];
        else if (t < 16) sB[t] = ((const float4*)b2)[t - 8];
    }
    __syncthreads();

    int tid = threadIdx.x;
    int n = blockIdx.x * 256 + tid;
    if (n >= N_NODES) return;   // no barriers below; safe to exit

    float pos = nodes[n*2+0];
    float vel = nodes[n*2+1];

    float y[32];
    #pragma unroll
    for (int j = 0; j < 10; ++j)
        y[j] = fmaf(pos, encW[j], fmaf(vel, encW[10+j], encb[j]));
    #pragma unroll
    for (int j = 0; j < 10; ++j) y[10+j] = sent[n*10+j];
    #pragma unroll
    for (int j = 0; j < 10; ++j) y[20+j] = recv[n*10+j];
    y[30] = globals_[0];
    y[31] = globals_[1];

    for (int s = 0; s < 10; ++s) {
        float k1[32], u[32], kt[32];
        // k1
        deriv32(sW1, sW2, sB, y, k1);
        #pragma unroll
        for (int j = 0; j < 32; ++j) u[j] = fmaf(Hc * A21c, k1[j], y[j]);
        // k2 -> LDS stash
        deriv32(sW1, sW2, sB, u, kt);
        #pragma unroll
        for (int j = 0; j < 32; ++j) {
            k2s[j][tid] = kt[j];
            u[j] = fmaf(Hc, fmaf(A31c, k1[j], A32c * kt[j]), y[j]);
        }
        // k3 -> LDS stash
        deriv32(sW1, sW2, sB, u, kt);
        #pragma unroll
        for (int j = 0; j < 32; ++j) {
            k3s[j][tid] = kt[j];
            u[j] = fmaf(Hc, fmaf(A41c, k1[j], fmaf(A42c, k2s[j][tid], A43c * kt[j])), y[j]);
        }
        // k4 (registers)
        float k4[32];
        deriv32(sW1, sW2, sB, u, k4);
        #pragma unroll
        for (int j = 0; j < 32; ++j)
            u[j] = fmaf(Hc, fmaf(A51c, k1[j], fmaf(A52c, k2s[j][tid],
                     fmaf(A53c, k3s[j][tid], A54c * k4[j]))), y[j]);
        // k5 (registers)
        float k5[32];
        deriv32(sW1, sW2, sB, u, k5);
        #pragma unroll
        for (int j = 0; j < 32; ++j)
            u[j] = fmaf(Hc, fmaf(A61c, k1[j], fmaf(A62c, k2s[j][tid],
                     fmaf(A63c, k3s[j][tid], fmaf(A64c, k4[j], A65c * k5[j])))), y[j]);
        // fold everything except k6 into y NOW -> k1,k4,k5 dead during last deriv
        #pragma unroll
        for (int j = 0; j < 32; ++j)
            y[j] = fmaf(Hc, fmaf(B1c, k1[j], fmaf(B3c, k3s[j][tid],
                     fmaf(B4c, k4[j], B5c * k5[j]))), y[j]);
        // k6
        deriv32(sW1, sW2, sB, u, kt);
        #pragma unroll
        for (int j = 0; j < 32; ++j)
            y[j] = fmaf(Hc * B6c, kt[j], y[j]);
    }

    // node_out: (32,10), then dec_node: (10,1)
    float h2[10];
    #pragma unroll
    for (int j = 0; j < 10; ++j) h2[j] = bno[j];
    #pragma unroll
    for (int i = 0; i < 32; ++i) {
        float v = y[i];
        #pragma unroll
        for (int j = 0; j < 10; ++j) h2[j] = fmaf(v, Wno[i*10+j], h2[j]);
    }
    float dn = bdn[0];
    #pragma unroll
    for (int j = 0; j < 10; ++j) dn = fmaf(h2[j], Wdn[j], dn);

    out_decn[n] = dn;
    float nv = vel + dn;   // DT = 1
    float np = pos + nv;
    out_pos[n] = np;
    out_vel[n] = nv;
}

extern "C" void kernel_launch(void* const* d_in, const int* in_sizes, int n_in,
                              void* d_out, int out_size, void* d_ws, size_t ws_size,
                              hipStream_t stream) {
    const float* nodes      = (const float*)d_in[0];
    const float* edges      = (const float*)d_in[1];
    const int*   senders    = (const int*)d_in[2];
    const int*   receivers  = (const int*)d_in[3];
    const float* globals_   = (const float*)d_in[4];
    const float* enc_node_W = (const float*)d_in[5];
    const float* enc_node_b = (const float*)d_in[6];
    const float* enc_edge_W = (const float*)d_in[7];
    const float* enc_edge_b = (const float*)d_in[8];
    const float* ode_W1     = (const float*)d_in[9];
    const float* ode_b1     = (const float*)d_in[10];
    const float* ode_W2     = (const float*)d_in[11];
    const float* ode_b2     = (const float*)d_in[12];
    const float* node_out_W = (const float*)d_in[13];
    const float* node_out_b = (const float*)d_in[14];
    const float* dec_node_W = (const float*)d_in[15];
    const float* dec_node_b = (const float*)d_in[16];
    const float* dec_edge_W = (const float*)d_in[17];
    const float* dec_edge_b = (const float*)d_in[18];

    float* out = (float*)d_out;
    float* out_decn = out;                       // [0, 1e5)
    float* out_dece = out + N_NODES;             // [1e5, 1.7e6)
    float* out_pos  = out + N_NODES + N_EDGES;   // [1.7e6, 1.8e6)
    float* out_vel  = out + 2*N_NODES + N_EDGES; // [1.8e6, 1.9e6)

    float* sent = (float*)d_ws;               // N_NODES*10 floats
    float* recv = sent + N_NODES*10;          // N_NODES*10 floats

    // 1) zero accumulators (2,000,000 floats = 500,000 float4)
    {
        int n4 = (N_NODES * 10 * 2) / 4;
        int blocks = (n4 + 255) / 256;
        zero_ws_kernel<<<blocks, 256, 0, stream>>>((float4*)d_ws, n4);
    }
    // 2) edge phase
    edge_kernel<<<(N_EDGES + 255) / 256, 256, 0, stream>>>(
        edges, senders, receivers, enc_edge_W, enc_edge_b,
        dec_edge_W, dec_edge_b, sent, recv, out_dece);
    // 3) node ODE phase
    node_kernel<<<(N_NODES + 255) / 256, 256, 0, stream>>>(
        nodes, globals_, enc_node_W, enc_node_b,
        ode_W1, ode_b1, ode_W2, ode_b2,
        node_out_W, node_out_b, dec_node_W, dec_node_b,
        sent, recv, out_decn, out_pos, out_vel);
}

// Round 3
// 12290.247 us; speedup vs baseline: 4.0810x; 4.0810x over previous
//
#include <hip/hip_runtime.h>
#include <hip/hip_bf16.h>

#define N_NODES 100000
#define N_EDGES 1600000

// ---- RK45 (Dormand-Prince) coefficients, fp32 ----
#define Hc   0.1f
#define A21c 0.2f
#define A31c (float)(3.0/40.0)
#define A32c (float)(9.0/40.0)
#define A41c (float)(44.0/45.0)
#define A42c (float)(-56.0/15.0)
#define A43c (float)(32.0/9.0)
#define A51c (float)(19372.0/6561.0)
#define A52c (float)(-25360.0/2187.0)
#define A53c (float)(64448.0/6561.0)
#define A54c (float)(-212.0/729.0)
#define A61c (float)(9017.0/3168.0)
#define A62c (float)(-355.0/33.0)
#define A63c (float)(46732.0/5247.0)
#define A64c (float)(49.0/176.0)
#define A65c (float)(-5103.0/18656.0)
#define B1c  (float)(35.0/384.0)
#define B3c  (float)(500.0/1113.0)
#define B4c  (float)(125.0/192.0)
#define B5c  (float)(-2187.0/6784.0)
#define B6c  (float)(11.0/84.0)

// Zero the segment-sum accumulators in workspace (re-poisoned 0xAA each call).
__global__ void zero_ws_kernel(float4* ws, int n4) {
    int i = blockIdx.x * blockDim.x + threadIdx.x;
    if (i < n4) ws[i] = make_float4(0.f, 0.f, 0.f, 0.f);
}

// Edge phase: encode edges, decode dec_e, scatter-add h_e into sent/recv sums.
__global__ __launch_bounds__(256) void edge_kernel(
    const float* __restrict__ edges,
    const int* __restrict__ senders,
    const int* __restrict__ receivers,
    const float* __restrict__ W,    // (3,10)
    const float* __restrict__ b,    // (10)
    const float* __restrict__ Wd,   // (10,1)
    const float* __restrict__ bd,   // (1)
    float* __restrict__ sent,       // (N_NODES,10) accumulators
    float* __restrict__ recv,       // (N_NODES,10) accumulators
    float* __restrict__ dec_e)      // (N_EDGES)
{
    int e = blockIdx.x * 256 + threadIdx.x;
    if (e >= N_EDGES) return;
    float e0 = edges[e*3+0], e1 = edges[e*3+1], e2 = edges[e*3+2];
    int s = senders[e], r = receivers[e];
    float he[10];
    float d = bd[0];
    #pragma unroll
    for (int j = 0; j < 10; ++j) {
        float v = fmaf(e0, W[j], fmaf(e1, W[10+j], fmaf(e2, W[20+j], b[j])));
        he[j] = v;
        d = fmaf(v, Wd[j], d);
    }
    dec_e[e] = d;
    #pragma unroll
    for (int j = 0; j < 10; ++j) atomicAdd(&sent[s*10+j], he[j]);
    #pragma unroll
    for (int j = 0; j < 10; ++j) atomicAdd(&recv[r*10+j], he[j]);
}

// One derivative eval, 2 lanes per node. Lane q owns output comps [16q,16q+16).
// in[16]/out[16] are this lane's slices. Full 32-wide input vector is
// reconstructed per-i via width-2 __shfl (DPP-cheap). Weights in LDS;
// per-instr 2 distinct addresses x 32-lane broadcast -> conflict-free.
__device__ __forceinline__ void deriv16(const float4* __restrict__ sW1,
                                        const float4* __restrict__ sW2,
                                        const float4* __restrict__ sB,  // [0..7]=b1,[8..15]=b2
                                        int q,
                                        const float* __restrict__ in,
                                        float* __restrict__ out)
{
    float t[16];
    #pragma unroll
    for (int c = 0; c < 4; ++c) {
        float4 bb = sB[q*4 + c];
        t[4*c+0] = bb.x; t[4*c+1] = bb.y; t[4*c+2] = bb.z; t[4*c+3] = bb.w;
    }
    #pragma unroll
    for (int i = 0; i < 32; ++i) {
        float v = __shfl(in[i & 15], i >> 4, 2);   // broadcast in[i] within lane pair
        #pragma unroll
        for (int c = 0; c < 4; ++c) {
            float4 w = sW1[i*8 + q*4 + c];
            t[4*c+0] = fmaf(v, w.x, t[4*c+0]);
            t[4*c+1] = fmaf(v, w.y, t[4*c+1]);
            t[4*c+2] = fmaf(v, w.z, t[4*c+2]);
            t[4*c+3] = fmaf(v, w.w, t[4*c+3]);
        }
    }
    #pragma unroll
    for (int j = 0; j < 16; ++j) t[j] = fmaxf(t[j], 0.0f);

    float o[16];
    #pragma unroll
    for (int c = 0; c < 4; ++c) {
        float4 bb = sB[8 + q*4 + c];
        o[4*c+0] = bb.x; o[4*c+1] = bb.y; o[4*c+2] = bb.z; o[4*c+3] = bb.w;
    }
    #pragma unroll
    for (int i = 0; i < 32; ++i) {
        float v = __shfl(t[i & 15], i >> 4, 2);
        #pragma unroll
        for (int c = 0; c < 4; ++c) {
            float4 w = sW2[i*8 + q*4 + c];
            o[4*c+0] = fmaf(v, w.x, o[4*c+0]);
            o[4*c+1] = fmaf(v, w.y, o[4*c+1]);
            o[4*c+2] = fmaf(v, w.z, o[4*c+2]);
            o[4*c+3] = fmaf(v, w.w, o[4*c+3]);
        }
    }
    #pragma unroll
    for (int j = 0; j < 16; ++j) out[j] = o[j];
}

// Node phase: 2 lanes per node, 16 state comps per lane. All k's in registers
// (~145 VGPR peak, far under the 256 arch limit -> no scratch possible).
__global__ __launch_bounds__(256) void node_kernel(
    const float* __restrict__ nodes,     // (N_NODES,2)
    const float* __restrict__ globals_,  // (2)
    const float* __restrict__ encW,      // (2,10)
    const float* __restrict__ encb,      // (10)
    const float* __restrict__ W1,        // (32,32)
    const float* __restrict__ b1,        // (32)
    const float* __restrict__ W2,        // (32,32)
    const float* __restrict__ b2,        // (32)
    const float* __restrict__ Wno,       // (32,10)
    const float* __restrict__ bno,       // (10)
    const float* __restrict__ Wdn,       // (10,1)
    const float* __restrict__ bdn,       // (1)
    const float* __restrict__ sent,      // (N_NODES,10)
    const float* __restrict__ recv,      // (N_NODES,10)
    float* __restrict__ out_decn,        // (N_NODES)
    float* __restrict__ out_pos,         // (N_NODES)
    float* __restrict__ out_vel)         // (N_NODES)
{
    __shared__ float4 sW1[256];
    __shared__ float4 sW2[256];
    __shared__ float4 sB[16];
    {
        int t = threadIdx.x;
        sW1[t] = ((const float4*)W1)[t];
        sW2[t] = ((const float4*)W2)[t];
        if (t < 8)  sB[t]      = ((const float4*)b1)[t];
        else if (t < 16) sB[t] = ((const float4*)b2)[t - 8];
    }
    __syncthreads();

    int tid = threadIdx.x;
    int q   = tid & 1;           // lane within node pair
    int n   = blockIdx.x * 128 + (tid >> 1);
    if (n >= N_NODES) return;    // pairs exit together; no barriers below

    float pos = nodes[n*2+0];
    float vel = nodes[n*2+1];

    // Assemble this lane's 16-comp slice of x = [h_n(10) | sent(10) | recv(10) | g(2)]
    float y[16];
    if (q == 0) {
        #pragma unroll
        for (int jj = 0; jj < 10; ++jj)
            y[jj] = fmaf(pos, encW[jj], fmaf(vel, encW[10+jj], encb[jj]));
        #pragma unroll
        for (int jj = 10; jj < 16; ++jj)
            y[jj] = sent[n*10 + (jj-10)];
    } else {
        #pragma unroll
        for (int jj = 0; jj < 4; ++jj)
            y[jj] = sent[n*10 + 6 + jj];
        #pragma unroll
        for (int jj = 4; jj < 14; ++jj)
            y[jj] = recv[n*10 + (jj-4)];
        y[14] = globals_[0];
        y[15] = globals_[1];
    }

    for (int s = 0; s < 10; ++s) {
        float k1[16], k2[16], k3[16], k4[16], k5[16], u[16], kt[16];
        deriv16(sW1, sW2, sB, q, y, k1);
        #pragma unroll
        for (int j = 0; j < 16; ++j) u[j] = fmaf(Hc * A21c, k1[j], y[j]);
        deriv16(sW1, sW2, sB, q, u, k2);
        #pragma unroll
        for (int j = 0; j < 16; ++j)
            u[j] = fmaf(Hc, fmaf(A31c, k1[j], A32c * k2[j]), y[j]);
        deriv16(sW1, sW2, sB, q, u, k3);
        #pragma unroll
        for (int j = 0; j < 16; ++j)
            u[j] = fmaf(Hc, fmaf(A41c, k1[j], fmaf(A42c, k2[j], A43c * k3[j])), y[j]);
        deriv16(sW1, sW2, sB, q, u, k4);
        #pragma unroll
        for (int j = 0; j < 16; ++j)
            u[j] = fmaf(Hc, fmaf(A51c, k1[j], fmaf(A52c, k2[j],
                     fmaf(A53c, k3[j], A54c * k4[j]))), y[j]);
        deriv16(sW1, sW2, sB, q, u, k5);
        #pragma unroll
        for (int j = 0; j < 16; ++j)
            u[j] = fmaf(Hc, fmaf(A61c, k1[j], fmaf(A62c, k2[j],
                     fmaf(A63c, k3[j], fmaf(A64c, k4[j], A65c * k5[j])))), y[j]);
        // fold B-sum (minus k6) into y now -> k1..k5 dead during last deriv
        #pragma unroll
        for (int j = 0; j < 16; ++j)
            y[j] = fmaf(Hc, fmaf(B1c, k1[j], fmaf(B3c, k3[j],
                     fmaf(B4c, k4[j], B5c * k5[j]))), y[j]);
        deriv16(sW1, sW2, sB, q, u, kt);
        #pragma unroll
        for (int j = 0; j < 16; ++j)
            y[j] = fmaf(Hc * B6c, kt[j], y[j]);
    }

    // node_out (32,10): partial with this lane's 16 comps, then pair-reduce.
    float p[10];
    #pragma unroll
    for (int jo = 0; jo < 10; ++jo) p[jo] = 0.0f;
    #pragma unroll
    for (int jj = 0; jj < 16; ++jj) {
        float v = y[jj];
        #pragma unroll
        for (int jo = 0; jo < 10; ++jo)
            p[jo] = fmaf(v, Wno[(16*q + jj)*10 + jo], p[jo]);
    }
    float dn = bdn[0];
    #pragma unroll
    for (int jo = 0; jo < 10; ++jo) {
        float h2 = p[jo] + __shfl_xor(p[jo], 1) + bno[jo];
        dn = fmaf(h2, Wdn[jo], dn);
    }

    if (q == 0) {
        out_decn[n] = dn;
        float nv = vel + dn;   // DT = 1
        float np = pos + nv;
        out_pos[n] = np;
        out_vel[n] = nv;
    }
}

extern "C" void kernel_launch(void* const* d_in, const int* in_sizes, int n_in,
                              void* d_out, int out_size, void* d_ws, size_t ws_size,
                              hipStream_t stream) {
    const float* nodes      = (const float*)d_in[0];
    const float* edges      = (const float*)d_in[1];
    const int*   senders    = (const int*)d_in[2];
    const int*   receivers  = (const int*)d_in[3];
    const float* globals_   = (const float*)d_in[4];
    const float* enc_node_W = (const float*)d_in[5];
    const float* enc_node_b = (const float*)d_in[6];
    const float* enc_edge_W = (const float*)d_in[7];
    const float* enc_edge_b = (const float*)d_in[8];
    const float* ode_W1     = (const float*)d_in[9];
    const float* ode_b1     = (const float*)d_in[10];
    const float* ode_W2     = (const float*)d_in[11];
    const float* ode_b2     = (const float*)d_in[12];
    const float* node_out_W = (const float*)d_in[13];
    const float* node_out_b = (const float*)d_in[14];
    const float* dec_node_W = (const float*)d_in[15];
    const float* dec_node_b = (const float*)d_in[16];
    const float* dec_edge_W = (const float*)d_in[17];
    const float* dec_edge_b = (const float*)d_in[18];

    float* out = (float*)d_out;
    float* out_decn = out;                       // [0, 1e5)
    float* out_dece = out + N_NODES;             // [1e5, 1.7e6)
    float* out_pos  = out + N_NODES + N_EDGES;   // [1.7e6, 1.8e6)
    float* out_vel  = out + 2*N_NODES + N_EDGES; // [1.8e6, 1.9e6)

    float* sent = (float*)d_ws;               // N_NODES*10 floats
    float* recv = sent + N_NODES*10;          // N_NODES*10 floats

    // 1) zero accumulators (2,000,000 floats = 500,000 float4)
    {
        int n4 = (N_NODES * 10 * 2) / 4;
        int blocks = (n4 + 255) / 256;
        zero_ws_kernel<<<blocks, 256, 0, stream>>>((float4*)d_ws, n4);
    }
    // 2) edge phase
    edge_kernel<<<(N_EDGES + 255) / 256, 256, 0, stream>>>(
        edges, senders, receivers, enc_edge_W, enc_edge_b,
        dec_edge_W, dec_edge_b, sent, recv, out_dece);
    // 3) node ODE phase: 2 lanes/node, 128 nodes per 256-thread block
    node_kernel<<<(N_NODES + 127) / 128, 256, 0, stream>>>(
        nodes, globals_, enc_node_W, enc_node_b,
        ode_W1, ode_b1, ode_W2, ode_b2,
        node_out_W, node_out_b, dec_node_W, dec_node_b,
        sent, recv, out_decn, out_pos, out_vel);
}

// Round 7
// 2501.509 us; speedup vs baseline: 20.0505x; 4.9131x over previous
//
#include <hip/hip_runtime.h>
#include <hip/hip_bf16.h>

#define N_NODES 100000
#define N_EDGES 1600000
#define N_STEPS 10

// ---- RK45 (Dormand-Prince) coefficients, fp32 ----
#define Hc   0.1f
#define A21c 0.2f
#define A31c (float)(3.0/40.0)
#define A32c (float)(9.0/40.0)
#define A41c (float)(44.0/45.0)
#define A42c (float)(-56.0/15.0)
#define A43c (float)(32.0/9.0)
#define A51c (float)(19372.0/6561.0)
#define A52c (float)(-25360.0/2187.0)
#define A53c (float)(64448.0/6561.0)
#define A54c (float)(-212.0/729.0)
#define A61c (float)(9017.0/3168.0)
#define A62c (float)(-355.0/33.0)
#define A63c (float)(46732.0/5247.0)
#define A64c (float)(49.0/176.0)
#define A65c (float)(-5103.0/18656.0)
#define B1c  (float)(35.0/384.0)
#define B3c  (float)(500.0/1113.0)
#define B4c  (float)(125.0/192.0)
#define B5c  (float)(-2187.0/6784.0)
#define B6c  (float)(11.0/84.0)

// Zero the segment-sum accumulators in workspace (re-poisoned 0xAA each call).
__global__ void zero_ws_kernel(float4* ws, int n4) {
    int i = blockIdx.x * blockDim.x + threadIdx.x;
    if (i < n4) ws[i] = make_float4(0.f, 0.f, 0.f, 0.f);
}

// Edge phase. gridDim.y = 2: y==0 -> sent side (+dec_e), y==1 -> recv side.
// Halves the per-thread atomic chain (10 instead of 20).
__global__ __launch_bounds__(256) void edge_kernel(
    const float* __restrict__ edges,
    const int* __restrict__ senders,
    const int* __restrict__ receivers,
    const float* __restrict__ W,    // (3,10)
    const float* __restrict__ b,    // (10)
    const float* __restrict__ Wd,   // (10,1)
    const float* __restrict__ bd,   // (1)
    float* __restrict__ sent,       // (N_NODES,10) accumulators
    float* __restrict__ recv,       // (N_NODES,10) accumulators
    float* __restrict__ dec_e)      // (N_EDGES)
{
    int e = blockIdx.x * 256 + threadIdx.x;
    if (e >= N_EDGES) return;
    int side = blockIdx.y;
    float e0 = edges[e*3+0], e1 = edges[e*3+1], e2 = edges[e*3+2];
    float he[10];
    #pragma unroll
    for (int j = 0; j < 10; ++j)
        he[j] = fmaf(e0, W[j], fmaf(e1, W[10+j], fmaf(e2, W[20+j], b[j])));
    if (side == 0) {
        float d = bd[0];
        #pragma unroll
        for (int j = 0; j < 10; ++j) d = fmaf(he[j], Wd[j], d);
        dec_e[e] = d;
        int s = senders[e];
        #pragma unroll
        for (int j = 0; j < 10; ++j) atomicAdd(&sent[s*10+j], he[j]);
    } else {
        int r = receivers[e];
        #pragma unroll
        for (int j = 0; j < 10; ++j) atomicAdd(&recv[r*10+j], he[j]);
    }
}

// One derivative eval, column-split across waves. Wave wq owns output cols
// [8wq, 8wq+8). u[8]/k[8] are this lane's node's slice. Full 32-vector is
// shared via LDS ([comp][node] b32, 2 lanes/bank = conflict-free). Weights
// are read at wave-uniform addresses -> scalar loads (K$), zero LDS traffic.
// Exactly 2 barriers; fixed buffers bufU/bufT are WAR-safe across calls
// because the next call's write to bufU happens after this call's barrier 2.
__device__ __forceinline__ void deriv8(
    float (* __restrict__ bufU)[64], float (* __restrict__ bufT)[64],
    int lane, int c0,
    const float* __restrict__ w1s,   // W1 + c0 (row-major 32x32)
    const float* __restrict__ w2s,   // W2 + c0
    const float* __restrict__ bb1,   // b1 slice [8]
    const float* __restrict__ bb2,   // b2 slice [8]
    const float* __restrict__ u, float* __restrict__ k)
{
    #pragma unroll
    for (int j = 0; j < 8; ++j) bufU[c0 + j][lane] = u[j];
    __syncthreads();
    float t[8];
    #pragma unroll
    for (int j = 0; j < 8; ++j) t[j] = bb1[j];
    #pragma unroll
    for (int i = 0; i < 32; ++i) {
        float v = bufU[i][lane];
        #pragma unroll
        for (int j = 0; j < 8; ++j) t[j] = fmaf(v, w1s[i*32 + j], t[j]);
    }
    #pragma unroll
    for (int j = 0; j < 8; ++j) t[j] = fmaxf(t[j], 0.0f);
    #pragma unroll
    for (int j = 0; j < 8; ++j) bufT[c0 + j][lane] = t[j];
    __syncthreads();
    #pragma unroll
    for (int j = 0; j < 8; ++j) k[j] = bb2[j];
    #pragma unroll
    for (int i = 0; i < 32; ++i) {
        float v = bufT[i][lane];
        #pragma unroll
        for (int j = 0; j < 8; ++j) k[j] = fmaf(v, w2s[i*32 + j], k[j]);
    }
}

// Node phase: block = 256 threads = 4 waves, 64 nodes/block (lane = node),
// wave wq owns state components [8wq, 8wq+8). Persistent per-lane state is
// only 64 floats -> no spill possible. Tail lanes clamp their node index and
// keep participating in barriers; stores are guarded.
__global__ __launch_bounds__(256) void node_kernel(
    const float* __restrict__ nodes,     // (N_NODES,2)
    const float* __restrict__ globals_,  // (2)
    const float* __restrict__ encW,      // (2,10)
    const float* __restrict__ encb,      // (10)
    const float* __restrict__ W1,        // (32,32)
    const float* __restrict__ b1,        // (32)
    const float* __restrict__ W2,        // (32,32)
    const float* __restrict__ b2,        // (32)
    const float* __restrict__ Wno,       // (32,10)
    const float* __restrict__ bno,       // (10)
    const float* __restrict__ Wdn,       // (10,1)
    const float* __restrict__ bdn,       // (1)
    const float* __restrict__ sent,      // (N_NODES,10)
    const float* __restrict__ recv,      // (N_NODES,10)
    float* __restrict__ out_decn,        // (N_NODES)
    float* __restrict__ out_pos,         // (N_NODES)
    float* __restrict__ out_vel)         // (N_NODES)
{
    __shared__ float xb[2][32][64];   // exchange buffers U,T (16 KB)

    const int tid  = threadIdx.x;
    const int lane = tid & 63;
    const int wq   = __builtin_amdgcn_readfirstlane(tid >> 6);
    const int c0   = wq * 8;
    const int n_raw = blockIdx.x * 64 + lane;
    const int n     = (n_raw < N_NODES) ? n_raw : (N_NODES - 1);

    const float* __restrict__ w1s = W1 + c0;
    const float* __restrict__ w2s = W2 + c0;
    float bb1[8], bb2[8];
    #pragma unroll
    for (int j = 0; j < 8; ++j) { bb1[j] = b1[c0+j]; bb2[j] = b2[c0+j]; }

    const float pos = nodes[n*2+0];
    const float vel = nodes[n*2+1];
    const float g0 = globals_[0], g1 = globals_[1];

    // Assemble this wave's 8-comp slice of x = [h_n(10)|sent(10)|recv(10)|g(2)]
    float y[8];
    #pragma unroll
    for (int j = 0; j < 8; ++j) {
        int c = c0 + j;
        float v;
        if (c < 10)      v = fmaf(pos, encW[c], fmaf(vel, encW[10+c], encb[c]));
        else if (c < 20) v = sent[n*10 + (c-10)];
        else if (c < 30) v = recv[n*10 + (c-20)];
        else             v = (c == 30) ? g0 : g1;
        y[j] = v;
    }

    for (int s = 0; s < N_STEPS; ++s) {
        float k1[8], k2[8], k3[8], k4[8], k5[8], kt[8], u[8];
        deriv8(xb[0], xb[1], lane, c0, w1s, w2s, bb1, bb2, y, k1);
        #pragma unroll
        for (int j = 0; j < 8; ++j) u[j] = fmaf(Hc * A21c, k1[j], y[j]);
        deriv8(xb[0], xb[1], lane, c0, w1s, w2s, bb1, bb2, u, k2);
        #pragma unroll
        for (int j = 0; j < 8; ++j)
            u[j] = fmaf(Hc, fmaf(A31c, k1[j], A32c * k2[j]), y[j]);
        deriv8(xb[0], xb[1], lane, c0, w1s, w2s, bb1, bb2, u, k3);
        #pragma unroll
        for (int j = 0; j < 8; ++j)
            u[j] = fmaf(Hc, fmaf(A41c, k1[j], fmaf(A42c, k2[j], A43c * k3[j])), y[j]);
        deriv8(xb[0], xb[1], lane, c0, w1s, w2s, bb1, bb2, u, k4);
        #pragma unroll
        for (int j = 0; j < 8; ++j)
            u[j] = fmaf(Hc, fmaf(A51c, k1[j], fmaf(A52c, k2[j],
                     fmaf(A53c, k3[j], A54c * k4[j]))), y[j]);
        deriv8(xb[0], xb[1], lane, c0, w1s, w2s, bb1, bb2, u, k5);
        #pragma unroll
        for (int j = 0; j < 8; ++j)
            u[j] = fmaf(Hc, fmaf(A61c, k1[j], fmaf(A62c, k2[j],
                     fmaf(A63c, k3[j], fmaf(A64c, k4[j], A65c * k5[j])))), y[j]);
        deriv8(xb[0], xb[1], lane, c0, w1s, w2s, bb1, bb2, u, kt);
        #pragma unroll
        for (int j = 0; j < 8; ++j)
            y[j] = fmaf(Hc, fmaf(B1c, k1[j], fmaf(B3c, k3[j],
                     fmaf(B4c, k4[j], fmaf(B5c, k5[j], B6c * kt[j])))), y[j]);
    }

    // node_out (32,10): per-wave partial over its 8 comps, reduce via LDS.
    float p[10];
    #pragma unroll
    for (int jo = 0; jo < 10; ++jo) p[jo] = 0.0f;
    #pragma unroll
    for (int j = 0; j < 8; ++j) {
        float v = y[j];
        #pragma unroll
        for (int jo = 0; jo < 10; ++jo)
            p[jo] = fmaf(v, Wno[(c0+j)*10 + jo], p[jo]);
    }
    __syncthreads();                       // xb free for reuse
    float* pb = &xb[0][0][0];              // reinterpret as [40][64]
    #pragma unroll
    for (int jo = 0; jo < 10; ++jo) pb[(wq*10 + jo)*64 + lane] = p[jo];
    __syncthreads();
    if (wq == 0 && n_raw < N_NODES) {
        float dn = bdn[0];
        #pragma unroll
        for (int jo = 0; jo < 10; ++jo) {
            float h2 = bno[jo] + pb[jo*64 + lane] + pb[(10+jo)*64 + lane]
                     + pb[(20+jo)*64 + lane] + pb[(30+jo)*64 + lane];
            dn = fmaf(h2, Wdn[jo], dn);
        }
        out_decn[n] = dn;
        float nv = vel + dn;   // DT = 1
        float np = pos + nv;
        out_pos[n] = np;
        out_vel[n] = nv;
    }
}

extern "C" void kernel_launch(void* const* d_in, const int* in_sizes, int n_in,
                              void* d_out, int out_size, void* d_ws, size_t ws_size,
                              hipStream_t stream) {
    const float* nodes      = (const float*)d_in[0];
    const float* edges      = (const float*)d_in[1];
    const int*   senders    = (const int*)d_in[2];
    const int*   receivers  = (const int*)d_in[3];
    const float* globals_   = (const float*)d_in[4];
    const float* enc_node_W = (const float*)d_in[5];
    const float* enc_node_b = (const float*)d_in[6];
    const float* enc_edge_W = (const float*)d_in[7];
    const float* enc_edge_b = (const float*)d_in[8];
    const float* ode_W1     = (const float*)d_in[9];
    const float* ode_b1     = (const float*)d_in[10];
    const float* ode_W2     = (const float*)d_in[11];
    const float* ode_b2     = (const float*)d_in[12];
    const float* node_out_W = (const float*)d_in[13];
    const float* node_out_b = (const float*)d_in[14];
    const float* dec_node_W = (const float*)d_in[15];
    const float* dec_node_b = (const float*)d_in[16];
    const float* dec_edge_W = (const float*)d_in[17];
    const float* dec_edge_b = (const float*)d_in[18];

    float* out = (float*)d_out;
    float* out_decn = out;                       // [0, 1e5)
    float* out_dece = out + N_NODES;             // [1e5, 1.7e6)
    float* out_pos  = out + N_NODES + N_EDGES;   // [1.7e6, 1.8e6)
    float* out_vel  = out + 2*N_NODES + N_EDGES; // [1.8e6, 1.9e6)

    float* sent = (float*)d_ws;               // N_NODES*10 floats
    float* recv = sent + N_NODES*10;          // N_NODES*10 floats

    // 1) zero accumulators (2,000,000 floats = 500,000 float4)
    {
        int n4 = (N_NODES * 10 * 2) / 4;
        int blocks = (n4 + 255) / 256;
        zero_ws_kernel<<<blocks, 256, 0, stream>>>((float4*)d_ws, n4);
    }
    // 2) edge phase (y=0: sent+dec_e, y=1: recv)
    {
        dim3 grid((N_EDGES + 255) / 256, 2);
        edge_kernel<<<grid, 256, 0, stream>>>(
            edges, senders, receivers, enc_edge_W, enc_edge_b,
            dec_edge_W, dec_edge_b, sent, recv, out_dece);
    }
    // 3) node ODE phase: 64 nodes per 256-thread block, col-split across waves
    node_kernel<<<(N_NODES + 63) / 64, 256, 0, stream>>>(
        nodes, globals_, enc_node_W, enc_node_b,
        ode_W1, ode_b1, ode_W2, ode_b2,
        node_out_W, node_out_b, dec_node_W, dec_node_b,
        sent, recv, out_decn, out_pos, out_vel);
}

// Round 9
// 2406.611 us; speedup vs baseline: 20.8411x; 1.0394x over previous
//
#include <hip/hip_runtime.h>
#include <hip/hip_bf16.h>

#define N_NODES 100000
#define N_EDGES 1600000
#define N_STEPS 10

// ---- RK45 (Dormand-Prince) coefficients, fp32 ----
#define Hc   0.1f
#define A21c 0.2f
#define A31c (float)(3.0/40.0)
#define A32c (float)(9.0/40.0)
#define A41c (float)(44.0/45.0)
#define A42c (float)(-56.0/15.0)
#define A43c (float)(32.0/9.0)
#define A51c (float)(19372.0/6561.0)
#define A52c (float)(-25360.0/2187.0)
#define A53c (float)(64448.0/6561.0)
#define A54c (float)(-212.0/729.0)
#define A61c (float)(9017.0/3168.0)
#define A62c (float)(-355.0/33.0)
#define A63c (float)(46732.0/5247.0)
#define A64c (float)(49.0/176.0)
#define A65c (float)(-5103.0/18656.0)
#define B1c  (float)(35.0/384.0)
#define B3c  (float)(500.0/1113.0)
#define B4c  (float)(125.0/192.0)
#define B5c  (float)(-2187.0/6784.0)
#define B6c  (float)(11.0/84.0)

// Zero the segment-sum accumulators in workspace (re-poisoned 0xAA each call).
__global__ void zero_ws_kernel(float4* ws, int n4) {
    int i = blockIdx.x * blockDim.x + threadIdx.x;
    if (i < n4) ws[i] = make_float4(0.f, 0.f, 0.f, 0.f);
}

// Edge phase. gridDim.y = 2: y==0 -> sent side (+dec_e), y==1 -> recv side.
// Accumulators are TRANSPOSED [comp][node]: a thread's 10 atomics go to 10
// widely-separated cache lines (vs 1 line before) -> 10x more line-level
// RMW parallelism. Node kernel reads become coalesced too.
__global__ __launch_bounds__(256) void edge_kernel(
    const float* __restrict__ edges,
    const int* __restrict__ senders,
    const int* __restrict__ receivers,
    const float* __restrict__ W,    // (3,10)
    const float* __restrict__ b,    // (10)
    const float* __restrict__ Wd,   // (10,1)
    const float* __restrict__ bd,   // (1)
    float* __restrict__ sent,       // (10, N_NODES) accumulators, comp-major
    float* __restrict__ recv,       // (10, N_NODES) accumulators, comp-major
    float* __restrict__ dec_e)      // (N_EDGES)
{
    int e = blockIdx.x * 256 + threadIdx.x;
    if (e >= N_EDGES) return;
    int side = blockIdx.y;
    float e0 = edges[e*3+0], e1 = edges[e*3+1], e2 = edges[e*3+2];
    float he[10];
    #pragma unroll
    for (int j = 0; j < 10; ++j)
        he[j] = fmaf(e0, W[j], fmaf(e1, W[10+j], fmaf(e2, W[20+j], b[j])));
    if (side == 0) {
        float d = bd[0];
        #pragma unroll
        for (int j = 0; j < 10; ++j) d = fmaf(he[j], Wd[j], d);
        dec_e[e] = d;
        int s = senders[e];
        #pragma unroll
        for (int j = 0; j < 10; ++j) atomicAdd(&sent[j*N_NODES + s], he[j]);
    } else {
        int r = receivers[e];
        #pragma unroll
        for (int j = 0; j < 10; ++j) atomicAdd(&recv[j*N_NODES + r], he[j]);
    }
}

// One derivative eval, column-split across waves. Wave wq owns output cols
// [8wq, 8wq+8). u[8]/k[8] are this lane's node's slice. Full 32-vector is
// shared via LDS ([comp][node] b32, 2 lanes/bank = conflict-free). Weights
// are read at wave-uniform addresses -> scalar loads (K$), zero LDS traffic.
// Exactly 2 barriers; fixed buffers bufU/bufT are WAR-safe across calls
// because the next call's write to bufU happens after this call's barrier 2.
__device__ __forceinline__ void deriv8(
    float (* __restrict__ bufU)[64], float (* __restrict__ bufT)[64],
    int lane, int c0,
    const float* __restrict__ w1s,   // W1 + c0 (row-major 32x32)
    const float* __restrict__ w2s,   // W2 + c0
    const float* __restrict__ bb1,   // b1 slice [8]
    const float* __restrict__ bb2,   // b2 slice [8]
    const float* __restrict__ u, float* __restrict__ k)
{
    #pragma unroll
    for (int j = 0; j < 8; ++j) bufU[c0 + j][lane] = u[j];
    __syncthreads();
    float t[8];
    #pragma unroll
    for (int j = 0; j < 8; ++j) t[j] = bb1[j];
    #pragma unroll
    for (int i = 0; i < 32; ++i) {
        float v = bufU[i][lane];
        #pragma unroll
        for (int j = 0; j < 8; ++j) t[j] = fmaf(v, w1s[i*32 + j], t[j]);
    }
    #pragma unroll
    for (int j = 0; j < 8; ++j) t[j] = fmaxf(t[j], 0.0f);
    #pragma unroll
    for (int j = 0; j < 8; ++j) bufT[c0 + j][lane] = t[j];
    __syncthreads();
    #pragma unroll
    for (int j = 0; j < 8; ++j) k[j] = bb2[j];
    #pragma unroll
    for (int i = 0; i < 32; ++i) {
        float v = bufT[i][lane];
        #pragma unroll
        for (int j = 0; j < 8; ++j) k[j] = fmaf(v, w2s[i*32 + j], k[j]);
    }
}

// Node phase: block = 256 threads = 4 waves, 64 nodes/block (lane = node),
// wave wq owns state components [8wq, 8wq+8). Persistent per-lane state is
// only 64 floats -> no spill possible. Tail lanes clamp their node index and
// keep participating in barriers; stores are guarded.
__global__ __launch_bounds__(256) void node_kernel(
    const float* __restrict__ nodes,     // (N_NODES,2)
    const float* __restrict__ globals_,  // (2)
    const float* __restrict__ encW,      // (2,10)
    const float* __restrict__ encb,      // (10)
    const float* __restrict__ W1,        // (32,32)
    const float* __restrict__ b1,        // (32)
    const float* __restrict__ W2,        // (32,32)
    const float* __restrict__ b2,        // (32)
    const float* __restrict__ Wno,       // (32,10)
    const float* __restrict__ bno,       // (10)
    const float* __restrict__ Wdn,       // (10,1)
    const float* __restrict__ bdn,       // (1)
    const float* __restrict__ sent,      // (10, N_NODES) comp-major
    const float* __restrict__ recv,      // (10, N_NODES) comp-major
    float* __restrict__ out_decn,        // (N_NODES)
    float* __restrict__ out_pos,         // (N_NODES)
    float* __restrict__ out_vel)         // (N_NODES)
{
    __shared__ float xb[2][32][64];   // exchange buffers U,T (16 KB)

    const int tid  = threadIdx.x;
    const int lane = tid & 63;
    const int wq   = __builtin_amdgcn_readfirstlane(tid >> 6);
    const int c0   = wq * 8;
    const int n_raw = blockIdx.x * 64 + lane;
    const int n     = (n_raw < N_NODES) ? n_raw : (N_NODES - 1);

    const float* __restrict__ w1s = W1 + c0;
    const float* __restrict__ w2s = W2 + c0;
    float bb1[8], bb2[8];
    #pragma unroll
    for (int j = 0; j < 8; ++j) { bb1[j] = b1[c0+j]; bb2[j] = b2[c0+j]; }

    const float pos = nodes[n*2+0];
    const float vel = nodes[n*2+1];
    const float g0 = globals_[0], g1 = globals_[1];

    // Assemble this wave's 8-comp slice of x = [h_n(10)|sent(10)|recv(10)|g(2)]
    // sent/recv are comp-major -> per-comp reads are lane-coalesced.
    float y[8];
    #pragma unroll
    for (int j = 0; j < 8; ++j) {
        int c = c0 + j;
        float v;
        if (c < 10)      v = fmaf(pos, encW[c], fmaf(vel, encW[10+c], encb[c]));
        else if (c < 20) v = sent[(c-10)*N_NODES + n];
        else if (c < 30) v = recv[(c-20)*N_NODES + n];
        else             v = (c == 30) ? g0 : g1;
        y[j] = v;
    }

    for (int s = 0; s < N_STEPS; ++s) {
        float k1[8], k2[8], k3[8], k4[8], k5[8], kt[8], u[8];
        deriv8(xb[0], xb[1], lane, c0, w1s, w2s, bb1, bb2, y, k1);
        #pragma unroll
        for (int j = 0; j < 8; ++j) u[j] = fmaf(Hc * A21c, k1[j], y[j]);
        deriv8(xb[0], xb[1], lane, c0, w1s, w2s, bb1, bb2, u, k2);
        #pragma unroll
        for (int j = 0; j < 8; ++j)
            u[j] = fmaf(Hc, fmaf(A31c, k1[j], A32c * k2[j]), y[j]);
        deriv8(xb[0], xb[1], lane, c0, w1s, w2s, bb1, bb2, u, k3);
        #pragma unroll
        for (int j = 0; j < 8; ++j)
            u[j] = fmaf(Hc, fmaf(A41c, k1[j], fmaf(A42c, k2[j], A43c * k3[j])), y[j]);
        deriv8(xb[0], xb[1], lane, c0, w1s, w2s, bb1, bb2, u, k4);
        #pragma unroll
        for (int j = 0; j < 8; ++j)
            u[j] = fmaf(Hc, fmaf(A51c, k1[j], fmaf(A52c, k2[j],
                     fmaf(A53c, k3[j], A54c * k4[j]))), y[j]);
        deriv8(xb[0], xb[1], lane, c0, w1s, w2s, bb1, bb2, u, k5);
        #pragma unroll
        for (int j = 0; j < 8; ++j)
            u[j] = fmaf(Hc, fmaf(A61c, k1[j], fmaf(A62c, k2[j],
                     fmaf(A63c, k3[j], fmaf(A64c, k4[j], A65c * k5[j])))), y[j]);
        deriv8(xb[0], xb[1], lane, c0, w1s, w2s, bb1, bb2, u, kt);
        #pragma unroll
        for (int j = 0; j < 8; ++j)
            y[j] = fmaf(Hc, fmaf(B1c, k1[j], fmaf(B3c, k3[j],
                     fmaf(B4c, k4[j], fmaf(B5c, k5[j], B6c * kt[j])))), y[j]);
    }

    // node_out (32,10): per-wave partial over its 8 comps, reduce via LDS.
    float p[10];
    #pragma unroll
    for (int jo = 0; jo < 10; ++jo) p[jo] = 0.0f;
    #pragma unroll
    for (int j = 0; j < 8; ++j) {
        float v = y[j];
        #pragma unroll
        for (int jo = 0; jo < 10; ++jo)
            p[jo] = fmaf(v, Wno[(c0+j)*10 + jo], p[jo]);
    }
    __syncthreads();                       // xb free for reuse
    float* pb = &xb[0][0][0];              // reinterpret as [40][64]
    #pragma unroll
    for (int jo = 0; jo < 10; ++jo) pb[(wq*10 + jo)*64 + lane] = p[jo];
    __syncthreads();
    if (wq == 0 && n_raw < N_NODES) {
        float dn = bdn[0];
        #pragma unroll
        for (int jo = 0; jo < 10; ++jo) {
            float h2 = bno[jo] + pb[jo*64 + lane] + pb[(10+jo)*64 + lane]
                     + pb[(20+jo)*64 + lane] + pb[(30+jo)*64 + lane];
            dn = fmaf(h2, Wdn[jo], dn);
        }
        out_decn[n] = dn;
        float nv = vel + dn;   // DT = 1
        float np = pos + nv;
        out_pos[n] = np;
        out_vel[n] = nv;
    }
}

extern "C" void kernel_launch(void* const* d_in, const int* in_sizes, int n_in,
                              void* d_out, int out_size, void* d_ws, size_t ws_size,
                              hipStream_t stream) {
    const float* nodes      = (const float*)d_in[0];
    const float* edges      = (const float*)d_in[1];
    const int*   senders    = (const int*)d_in[2];
    const int*   receivers  = (const int*)d_in[3];
    const float* globals_   = (const float*)d_in[4];
    const float* enc_node_W = (const float*)d_in[5];
    const float* enc_node_b = (const float*)d_in[6];
    const float* enc_edge_W = (const float*)d_in[7];
    const float* enc_edge_b = (const float*)d_in[8];
    const float* ode_W1     = (const float*)d_in[9];
    const float* ode_b1     = (const float*)d_in[10];
    const float* ode_W2     = (const float*)d_in[11];
    const float* ode_b2     = (const float*)d_in[12];
    const float* node_out_W = (const float*)d_in[13];
    const float* node_out_b = (const float*)d_in[14];
    const float* dec_node_W = (const float*)d_in[15];
    const float* dec_node_b = (const float*)d_in[16];
    const float* dec_edge_W = (const float*)d_in[17];
    const float* dec_edge_b = (const float*)d_in[18];

    float* out = (float*)d_out;
    float* out_decn = out;                       // [0, 1e5)
    float* out_dece = out + N_NODES;             // [1e5, 1.7e6)
    float* out_pos  = out + N_NODES + N_EDGES;   // [1.7e6, 1.8e6)
    float* out_vel  = out + 2*N_NODES + N_EDGES; // [1.8e6, 1.9e6)

    float* sent = (float*)d_ws;               // (10, N_NODES) comp-major
    float* recv = sent + N_NODES*10;          // (10, N_NODES) comp-major

    // 1) zero accumulators (2,000,000 floats = 500,000 float4)
    {
        int n4 = (N_NODES * 10 * 2) / 4;
        int blocks = (n4 + 255) / 256;
        zero_ws_kernel<<<blocks, 256, 0, stream>>>((float4*)d_ws, n4);
    }
    // 2) edge phase (y=0: sent+dec_e, y=1: recv)
    {
        dim3 grid((N_EDGES + 255) / 256, 2);
        edge_kernel<<<grid, 256, 0, stream>>>(
            edges, senders, receivers, enc_edge_W, enc_edge_b,
            dec_edge_W, dec_edge_b, sent, recv, out_dece);
    }
    // 3) node ODE phase: 64 nodes per 256-thread block, col-split across waves
    node_kernel<<<(N_NODES + 63) / 64, 256, 0, stream>>>(
        nodes, globals_, enc_node_W, enc_node_b,
        ode_W1, ode_b1, ode_W2, ode_b2,
        node_out_W, node_out_b, dec_node_W, dec_node_b,
        sent, recv, out_decn, out_pos, out_vel);
}

// Round 10
// 1423.439 us; speedup vs baseline: 35.2361x; 1.6907x over previous
//
#include <hip/hip_runtime.h>
#include <hip/hip_bf16.h>

#define N_NODES 100000
#define N_EDGES 1600000
#define N_STEPS 10

// ---- RK45 (Dormand-Prince) coefficients, fp32 ----
#define Hc   0.1f
#define A21c 0.2f
#define A31c (float)(3.0/40.0)
#define A32c (float)(9.0/40.0)
#define A41c (float)(44.0/45.0)
#define A42c (float)(-56.0/15.0)
#define A43c (float)(32.0/9.0)
#define A51c (float)(19372.0/6561.0)
#define A52c (float)(-25360.0/2187.0)
#define A53c (float)(64448.0/6561.0)
#define A54c (float)(-212.0/729.0)
#define A61c (float)(9017.0/3168.0)
#define A62c (float)(-355.0/33.0)
#define A63c (float)(46732.0/5247.0)
#define A64c (float)(49.0/176.0)
#define A65c (float)(-5103.0/18656.0)
#define B1c  (float)(35.0/384.0)
#define B3c  (float)(500.0/1113.0)
#define B4c  (float)(125.0/192.0)
#define B5c  (float)(-2187.0/6784.0)
#define B6c  (float)(11.0/84.0)

// Zero workspace region (re-poisoned 0xAA each call).
__global__ void zero_ws_kernel(float4* ws, int n4) {
    int i = blockIdx.x * blockDim.x + threadIdx.x;
    if (i < n4) ws[i] = make_float4(0.f, 0.f, 0.f, 0.f);
}

// ============ CSR path (3.2M int atomics instead of 32M float) ============

// Per edge: dec_e output; count sender/receiver occupancy and remember the
// within-node position (pos). 2 int atomics per edge.
__global__ __launch_bounds__(256) void encode_count_kernel(
    const float* __restrict__ edges,
    const int* __restrict__ senders,
    const int* __restrict__ receivers,
    const float* __restrict__ W,    // (3,10)
    const float* __restrict__ b,    // (10)
    const float* __restrict__ Wd,   // (10,1)
    const float* __restrict__ bd,   // (1)
    int* __restrict__ cnt,          // (2*N_NODES) counters, zeroed
    int* __restrict__ pos_s,        // (N_EDGES)
    int* __restrict__ pos_r,        // (N_EDGES)
    float* __restrict__ dec_e)      // (N_EDGES)
{
    int e = blockIdx.x * 256 + threadIdx.x;
    if (e >= N_EDGES) return;
    float e0 = edges[e*3+0], e1 = edges[e*3+1], e2 = edges[e*3+2];
    float d = bd[0];
    #pragma unroll
    for (int j = 0; j < 10; ++j) {
        float he = fmaf(e0, W[j], fmaf(e1, W[10+j], fmaf(e2, W[20+j], b[j])));
        d = fmaf(he, Wd[j], d);
    }
    dec_e[e] = d;
    int s = senders[e], r = receivers[e];
    pos_s[e] = atomicAdd(&cnt[s], 1);
    pos_r[e] = atomicAdd(&cnt[N_NODES + r], 1);
}

// Single-block exclusive scan of n ints in-place (n = 200000).
__global__ __launch_bounds__(1024) void scan_kernel(int* __restrict__ data, int n) {
    __shared__ int lds[1024];
    const int t = threadIdx.x;
    const int CH = (n + 1023) / 1024;
    int lo = t * CH;
    int hi = lo + CH; if (hi > n) hi = n;
    int sum = 0;
    for (int i = lo; i < hi; ++i) sum += data[i];
    lds[t] = sum;
    __syncthreads();
    for (int off = 1; off < 1024; off <<= 1) {
        int v = (t >= off) ? lds[t - off] : 0;
        __syncthreads();
        lds[t] += v;
        __syncthreads();
    }
    int run = (t == 0) ? 0 : lds[t - 1];
    for (int i = lo; i < hi; ++i) {
        int v = data[i];
        data[i] = run;
        run += v;
    }
}

// Scatter edge ids into CSR slot arrays. No atomics.
__global__ __launch_bounds__(256) void scatter_kernel(
    const int* __restrict__ senders,
    const int* __restrict__ receivers,
    const int* __restrict__ base,   // (2*N_NODES) exclusive prefixes
    const int* __restrict__ pos_s,
    const int* __restrict__ pos_r,
    int* __restrict__ eid)          // (2*N_EDGES)
{
    int e = blockIdx.x * 256 + threadIdx.x;
    if (e >= N_EDGES) return;
    int s = senders[e];
    eid[base[s] + pos_s[e]] = e;
    int r = receivers[e];
    eid[base[N_NODES + r] + pos_r[e]] = e;
}

// Per node+side: walk edge list, recompute h_e (edges array is L2/L3-hot),
// sum, write comp-major sent/recv (coalesced per comp).
__global__ __launch_bounds__(256) void gather_kernel(
    const float* __restrict__ edges,
    const float* __restrict__ W,    // (3,10)
    const float* __restrict__ b,    // (10)
    const int* __restrict__ base,   // (2*N_NODES)
    const int* __restrict__ eid,    // (2*N_EDGES)
    float* __restrict__ sent,       // (10, N_NODES)
    float* __restrict__ recv)       // (10, N_NODES)
{
    int n = blockIdx.x * 256 + threadIdx.x;
    if (n >= N_NODES) return;
    int side = blockIdx.y;
    int idx = side * N_NODES + n;
    int start = base[idx];
    int end = (idx + 1 < 2*N_NODES) ? base[idx + 1] : 2*N_EDGES;
    float acc[10];
    #pragma unroll
    for (int j = 0; j < 10; ++j) acc[j] = 0.0f;
    for (int p = start; p < end; ++p) {
        int e = eid[p];
        float e0 = edges[e*3+0], e1 = edges[e*3+1], e2 = edges[e*3+2];
        #pragma unroll
        for (int j = 0; j < 10; ++j)
            acc[j] += fmaf(e0, W[j], fmaf(e1, W[10+j], fmaf(e2, W[20+j], b[j])));
    }
    float* dst = side ? recv : sent;
    #pragma unroll
    for (int j = 0; j < 10; ++j) dst[j*N_NODES + n] = acc[j];
}

// ============ Fallback: measured round-9 atomic path ============

__global__ __launch_bounds__(256) void edge_kernel(
    const float* __restrict__ edges,
    const int* __restrict__ senders,
    const int* __restrict__ receivers,
    const float* __restrict__ W,
    const float* __restrict__ b,
    const float* __restrict__ Wd,
    const float* __restrict__ bd,
    float* __restrict__ sent,       // (10, N_NODES)
    float* __restrict__ recv,       // (10, N_NODES)
    float* __restrict__ dec_e)
{
    int e = blockIdx.x * 256 + threadIdx.x;
    if (e >= N_EDGES) return;
    int side = blockIdx.y;
    float e0 = edges[e*3+0], e1 = edges[e*3+1], e2 = edges[e*3+2];
    float he[10];
    #pragma unroll
    for (int j = 0; j < 10; ++j)
        he[j] = fmaf(e0, W[j], fmaf(e1, W[10+j], fmaf(e2, W[20+j], b[j])));
    if (side == 0) {
        float d = bd[0];
        #pragma unroll
        for (int j = 0; j < 10; ++j) d = fmaf(he[j], Wd[j], d);
        dec_e[e] = d;
        int s = senders[e];
        #pragma unroll
        for (int j = 0; j < 10; ++j) atomicAdd(&sent[j*N_NODES + s], he[j]);
    } else {
        int r = receivers[e];
        #pragma unroll
        for (int j = 0; j < 10; ++j) atomicAdd(&recv[j*N_NODES + r], he[j]);
    }
}

// ============ Node ODE phase (unchanged from round 9) ============

__device__ __forceinline__ void deriv8(
    float (* __restrict__ bufU)[64], float (* __restrict__ bufT)[64],
    int lane, int c0,
    const float* __restrict__ w1s,
    const float* __restrict__ w2s,
    const float* __restrict__ bb1,
    const float* __restrict__ bb2,
    const float* __restrict__ u, float* __restrict__ k)
{
    #pragma unroll
    for (int j = 0; j < 8; ++j) bufU[c0 + j][lane] = u[j];
    __syncthreads();
    float t[8];
    #pragma unroll
    for (int j = 0; j < 8; ++j) t[j] = bb1[j];
    #pragma unroll
    for (int i = 0; i < 32; ++i) {
        float v = bufU[i][lane];
        #pragma unroll
        for (int j = 0; j < 8; ++j) t[j] = fmaf(v, w1s[i*32 + j], t[j]);
    }
    #pragma unroll
    for (int j = 0; j < 8; ++j) t[j] = fmaxf(t[j], 0.0f);
    #pragma unroll
    for (int j = 0; j < 8; ++j) bufT[c0 + j][lane] = t[j];
    __syncthreads();
    #pragma unroll
    for (int j = 0; j < 8; ++j) k[j] = bb2[j];
    #pragma unroll
    for (int i = 0; i < 32; ++i) {
        float v = bufT[i][lane];
        #pragma unroll
        for (int j = 0; j < 8; ++j) k[j] = fmaf(v, w2s[i*32 + j], k[j]);
    }
}

__global__ __launch_bounds__(256) void node_kernel(
    const float* __restrict__ nodes,
    const float* __restrict__ globals_,
    const float* __restrict__ encW,
    const float* __restrict__ encb,
    const float* __restrict__ W1,
    const float* __restrict__ b1,
    const float* __restrict__ W2,
    const float* __restrict__ b2,
    const float* __restrict__ Wno,
    const float* __restrict__ bno,
    const float* __restrict__ Wdn,
    const float* __restrict__ bdn,
    const float* __restrict__ sent,      // (10, N_NODES) comp-major
    const float* __restrict__ recv,      // (10, N_NODES) comp-major
    float* __restrict__ out_decn,
    float* __restrict__ out_pos,
    float* __restrict__ out_vel)
{
    __shared__ float xb[2][32][64];

    const int tid  = threadIdx.x;
    const int lane = tid & 63;
    const int wq   = __builtin_amdgcn_readfirstlane(tid >> 6);
    const int c0   = wq * 8;
    const int n_raw = blockIdx.x * 64 + lane;
    const int n     = (n_raw < N_NODES) ? n_raw : (N_NODES - 1);

    const float* __restrict__ w1s = W1 + c0;
    const float* __restrict__ w2s = W2 + c0;
    float bb1[8], bb2[8];
    #pragma unroll
    for (int j = 0; j < 8; ++j) { bb1[j] = b1[c0+j]; bb2[j] = b2[c0+j]; }

    const float pos = nodes[n*2+0];
    const float vel = nodes[n*2+1];
    const float g0 = globals_[0], g1 = globals_[1];

    float y[8];
    #pragma unroll
    for (int j = 0; j < 8; ++j) {
        int c = c0 + j;
        float v;
        if (c < 10)      v = fmaf(pos, encW[c], fmaf(vel, encW[10+c], encb[c]));
        else if (c < 20) v = sent[(c-10)*N_NODES + n];
        else if (c < 30) v = recv[(c-20)*N_NODES + n];
        else             v = (c == 30) ? g0 : g1;
        y[j] = v;
    }

    for (int s = 0; s < N_STEPS; ++s) {
        float k1[8], k2[8], k3[8], k4[8], k5[8], kt[8], u[8];
        deriv8(xb[0], xb[1], lane, c0, w1s, w2s, bb1, bb2, y, k1);
        #pragma unroll
        for (int j = 0; j < 8; ++j) u[j] = fmaf(Hc * A21c, k1[j], y[j]);
        deriv8(xb[0], xb[1], lane, c0, w1s, w2s, bb1, bb2, u, k2);
        #pragma unroll
        for (int j = 0; j < 8; ++j)
            u[j] = fmaf(Hc, fmaf(A31c, k1[j], A32c * k2[j]), y[j]);
        deriv8(xb[0], xb[1], lane, c0, w1s, w2s, bb1, bb2, u, k3);
        #pragma unroll
        for (int j = 0; j < 8; ++j)
            u[j] = fmaf(Hc, fmaf(A41c, k1[j], fmaf(A42c, k2[j], A43c * k3[j])), y[j]);
        deriv8(xb[0], xb[1], lane, c0, w1s, w2s, bb1, bb2, u, k4);
        #pragma unroll
        for (int j = 0; j < 8; ++j)
            u[j] = fmaf(Hc, fmaf(A51c, k1[j], fmaf(A52c, k2[j],
                     fmaf(A53c, k3[j], A54c * k4[j]))), y[j]);
        deriv8(xb[0], xb[1], lane, c0, w1s, w2s, bb1, bb2, u, k5);
        #pragma unroll
        for (int j = 0; j < 8; ++j)
            u[j] = fmaf(Hc, fmaf(A61c, k1[j], fmaf(A62c, k2[j],
                     fmaf(A63c, k3[j], fmaf(A64c, k4[j], A65c * k5[j])))), y[j]);
        deriv8(xb[0], xb[1], lane, c0, w1s, w2s, bb1, bb2, u, kt);
        #pragma unroll
        for (int j = 0; j < 8; ++j)
            y[j] = fmaf(Hc, fmaf(B1c, k1[j], fmaf(B3c, k3[j],
                     fmaf(B4c, k4[j], fmaf(B5c, k5[j], B6c * kt[j])))), y[j]);
    }

    float p[10];
    #pragma unroll
    for (int jo = 0; jo < 10; ++jo) p[jo] = 0.0f;
    #pragma unroll
    for (int j = 0; j < 8; ++j) {
        float v = y[j];
        #pragma unroll
        for (int jo = 0; jo < 10; ++jo)
            p[jo] = fmaf(v, Wno[(c0+j)*10 + jo], p[jo]);
    }
    __syncthreads();
    float* pb = &xb[0][0][0];
    #pragma unroll
    for (int jo = 0; jo < 10; ++jo) pb[(wq*10 + jo)*64 + lane] = p[jo];
    __syncthreads();
    if (wq == 0 && n_raw < N_NODES) {
        float dn = bdn[0];
        #pragma unroll
        for (int jo = 0; jo < 10; ++jo) {
            float h2 = bno[jo] + pb[jo*64 + lane] + pb[(10+jo)*64 + lane]
                     + pb[(20+jo)*64 + lane] + pb[(30+jo)*64 + lane];
            dn = fmaf(h2, Wdn[jo], dn);
        }
        out_decn[n] = dn;
        float nv = vel + dn;   // DT = 1
        float np = pos + nv;
        out_pos[n] = np;
        out_vel[n] = nv;
    }
}

extern "C" void kernel_launch(void* const* d_in, const int* in_sizes, int n_in,
                              void* d_out, int out_size, void* d_ws, size_t ws_size,
                              hipStream_t stream) {
    const float* nodes      = (const float*)d_in[0];
    const float* edges      = (const float*)d_in[1];
    const int*   senders    = (const int*)d_in[2];
    const int*   receivers  = (const int*)d_in[3];
    const float* globals_   = (const float*)d_in[4];
    const float* enc_node_W = (const float*)d_in[5];
    const float* enc_node_b = (const float*)d_in[6];
    const float* enc_edge_W = (const float*)d_in[7];
    const float* enc_edge_b = (const float*)d_in[8];
    const float* ode_W1     = (const float*)d_in[9];
    const float* ode_b1     = (const float*)d_in[10];
    const float* ode_W2     = (const float*)d_in[11];
    const float* ode_b2     = (const float*)d_in[12];
    const float* node_out_W = (const float*)d_in[13];
    const float* node_out_b = (const float*)d_in[14];
    const float* dec_node_W = (const float*)d_in[15];
    const float* dec_node_b = (const float*)d_in[16];
    const float* dec_edge_W = (const float*)d_in[17];
    const float* dec_edge_b = (const float*)d_in[18];

    float* out = (float*)d_out;
    float* out_decn = out;                       // [0, 1e5)
    float* out_dece = out + N_NODES;             // [1e5, 1.7e6)
    float* out_pos  = out + N_NODES + N_EDGES;   // [1.7e6, 1.8e6)
    float* out_vel  = out + 2*N_NODES + N_EDGES; // [1.8e6, 1.9e6)

    // Workspace layout
    float* sent = (float*)d_ws;                    // 10*N floats
    float* recv = sent + 10*N_NODES;               // 10*N floats
    int*   base = (int*)(recv + 10*N_NODES);       // 2*N ints (counts -> bases)
    int*   pos_s = base + 2*N_NODES;               // N_EDGES ints
    int*   pos_r = pos_s + N_EDGES;                // N_EDGES ints
    int*   eid   = pos_r + N_EDGES;                // 2*N_EDGES ints

    size_t need = (size_t)(20*N_NODES)*4 + (size_t)(2*N_NODES)*4
                + (size_t)(4*N_EDGES)*4;           // = 34.4 MB

    if (ws_size >= need) {
        // ---- CSR path ----
        // 1) zero counters (2*N ints = 50000 float4)
        zero_ws_kernel<<<(50000 + 255) / 256, 256, 0, stream>>>(
            (float4*)base, 50000);
        // 2) encode + count (2 int atomics per edge)
        encode_count_kernel<<<(N_EDGES + 255) / 256, 256, 0, stream>>>(
            edges, senders, receivers, enc_edge_W, enc_edge_b,
            dec_edge_W, dec_edge_b, base, pos_s, pos_r, out_dece);
        // 3) exclusive scan of concatenated counters
        scan_kernel<<<1, 1024, 0, stream>>>(base, 2*N_NODES);
        // 4) scatter edge ids (no atomics)
        scatter_kernel<<<(N_EDGES + 255) / 256, 256, 0, stream>>>(
            senders, receivers, base, pos_s, pos_r, eid);
        // 5) gather: recompute h_e, sum per node, write comp-major
        {
            dim3 grid((N_NODES + 255) / 256, 2);
            gather_kernel<<<grid, 256, 0, stream>>>(
                edges, enc_edge_W, enc_edge_b, base, eid, sent, recv);
        }
    } else {
        // ---- fallback: round-9 atomic path ----
        int n4 = (N_NODES * 10 * 2) / 4;
        zero_ws_kernel<<<(n4 + 255) / 256, 256, 0, stream>>>((float4*)d_ws, n4);
        dim3 grid((N_EDGES + 255) / 256, 2);
        edge_kernel<<<grid, 256, 0, stream>>>(
            edges, senders, receivers, enc_edge_W, enc_edge_b,
            dec_edge_W, dec_edge_b, sent, recv, out_dece);
    }

    // node ODE phase (unchanged)
    node_kernel<<<(N_NODES + 63) / 64, 256, 0, stream>>>(
        nodes, globals_, enc_node_W, enc_node_b,
        ode_W1, ode_b1, ode_W2, ode_b2,
        node_out_W, node_out_b, dec_node_W, dec_node_b,
        sent, recv, out_decn, out_pos, out_vel);
}